// Round 5
// baseline (193.676 us; speedup 1.0000x reference)
//
#include <hip/hip_runtime.h>

// YOLO loss, fp32. predictions: (batch,7,7,13), target: (batch,7,7,8), out: scalar.
// R4 post-mortem: warm replays (FETCH~0, L3-resident) run at the SAME 50us as
// cold -> not BW-bound; the global_load_lds + vmcnt(0)-drain structure
// serializes issue->use every iteration (LDS dest = no precise waitcnt).
// R5: register-destination coalesced loads (precise per-reg vmcnt) + wave-
// private LDS transpose slab + manual depth-2 pipeline. No __syncthreads,
// no global_load_lds in the hot loop.

static constexpr int PRED_C = 13;   // 5*B + C
static constexpr int TGT_C  = 8;    // 1 + 4 + 3
static constexpr float L_NOOBJ = 0.5f;
static constexpr float L_COORD = 5.0f;
static constexpr float EPSI = 1e-6f;

static constexpr int TILE    = 256;                 // cells per wave-tile
static constexpr int SLAB4   = TILE * PRED_C / 4;   // 832 float4 = 13312 B/wave
static constexpr int NBLOCKS = 768;                 // 53.3 KB LDS -> 3 blocks/CU exact

__device__ __forceinline__ float iou_f(float ax, float ay, float aw, float ah,
                                       float bx, float by, float bw, float bh) {
    float ax1 = ax - aw * 0.5f, ax2 = ax + aw * 0.5f;
    float ay1 = ay - ah * 0.5f, ay2 = ay + ah * 0.5f;
    float bx1 = bx - bw * 0.5f, bx2 = bx + bw * 0.5f;
    float by1 = by - bh * 0.5f, by2 = by + bh * 0.5f;
    float iw = fmaxf(fminf(ax2, bx2) - fmaxf(ax1, bx1), 0.0f);
    float ih = fmaxf(fminf(ay2, by2) - fmaxf(ay1, by1), 0.0f);
    float inter = iw * ih;
    float uni = (ax2 - ax1) * (ay2 - ay1) + (bx2 - bx1) * (by2 - by1) - inter;
    return inter / (uni + EPSI);
}

// ta = target floats 0..3 (obj,x,y,w), tb = floats 4..7 (h, c0,c1,c2)
__device__ __forceinline__ float cell_loss(const float* __restrict__ p,
                                           float4 ta, float4 tb) {
    float m  = (ta.x == 1.0f) ? 1.0f : 0.0f;
    float tx = ta.y, ty = ta.z, tw = ta.w, th = tb.x;

    float b1c = p[0],  b1x = p[1],  b1y = p[2],  b1w = p[3], b1h = p[4];
    float b2c = p[5],  b2x = p[6],  b2y = p[7],  b2w = p[8], b2h = p[9];

    float i1 = iou_f(b1x, b1y, b1w, b1h, tx, ty, tw, th);
    float i2 = iou_f(b2x, b2y, b2w, b2h, tx, ty, tw, th);
    bool pick1 = i1 > i2;
    float iou = pick1 ? i1 : i2;
    float sc  = pick1 ? b1c : b2c;
    float sx  = pick1 ? b1x : b2x;
    float sy  = pick1 ? b1y : b2y;
    float sw  = pick1 ? b1w : b2w;
    float sh  = pick1 ? b1h : b2h;
    float uc  = pick1 ? b2c : b1c;

    float dx = sx - tx, dy = sy - ty;
    // sign(w)*sqrt(|w|): copysign matches jnp.sign semantics for finite inputs.
    float dw = copysignf(sqrtf(fabsf(sw)), sw) - sqrtf(tw);
    float dh = copysignf(sqrtf(fabsf(sh)), sh) - sqrtf(th);
    float l_coord = dx * dx + dy * dy + dw * dw + dh * dh;

    float doj = sc - iou;
    float d0 = p[10] - tb.y, d1 = p[11] - tb.z, d2 = p[12] - tb.w;
    float l_cls = d0 * d0 + d1 * d1 + d2 * d2;
    float l_noobj = m * uc * uc + (1.0f - m) * (b1c * b1c + b2c * b2c);

    return m * (L_COORD * l_coord + doj * doj + l_cls) + L_NOOBJ * l_noobj;
}

__global__ __launch_bounds__(256) void yolo_main(const float* __restrict__ pred,
                                                 const float* __restrict__ tgt,
                                                 float* __restrict__ partial,
                                                 long long ntiles, long long ncells) {
    __shared__ float4 sp4[4][SLAB4];   // wave-private 13312 B slab each
    __shared__ float wsum[4];

    const int t    = threadIdx.x;
    const int lane = t & 63;
    const int wave = t >> 6;
    float4* slab4 = sp4[wave];
    const float* slabf = (const float*)slab4;

    const long long nw = (long long)gridDim.x * 4;
    long long tile = (long long)blockIdx.x * 4 + wave;

    float acc = 0.0f;
    float4 P[13];   // pred tile, identity-layout float4s (lane-stride 16B loads)
    float4 T[8];    // targets for my 4 cells (cells tile*256 + 64k + lane)

    auto issue = [&](long long tl) {
        const long long cb = tl * TILE;
        const float4* gp4 = (const float4*)(pred + cb * PRED_C);
#pragma unroll
        for (int r = 0; r < 13; ++r) P[r] = gp4[r * 64 + lane];
#pragma unroll
        for (int k = 0; k < 4; ++k) {
            const float4* gt4 = (const float4*)(tgt + (cb + 64 * k + lane) * TGT_C);
            T[2 * k]     = gt4[0];
            T[2 * k + 1] = gt4[1];
        }
    };
    auto full = [&](long long tl) { return (tl + 1) * TILE <= ncells; };

    bool curFull = false;
    if (tile < ntiles) {
        curFull = full(tile);
        if (curFull) issue(tile);          // prologue: loads in flight
    }

    while (tile < ntiles) {
        const long long next = tile + nw;
        const bool nextFull = (next < ntiles) && full(next);

        if (curFull) {
            // park pred tile in LDS (compiler waits precisely on P's vmcnt)
#pragma unroll
            for (int r = 0; r < 13; ++r) slab4[r * 64 + lane] = P[r];
            // snapshot targets (frees T for the next issue)
            float4 ta0 = T[0], tb0 = T[1], ta1 = T[2], tb1 = T[3];
            float4 ta2 = T[4], tb2 = T[5], ta3 = T[6], tb3 = T[7];

            if (nextFull) issue(next);     // next tile's 21 loads fly during compute

            float pb[PRED_C];
#pragma unroll
            for (int i = 0; i < PRED_C; ++i) pb[i] = slabf[lane * PRED_C + i];
            acc += cell_loss(pb, ta0, tb0);
#pragma unroll
            for (int i = 0; i < PRED_C; ++i) pb[i] = slabf[(64 + lane) * PRED_C + i];
            acc += cell_loss(pb, ta1, tb1);
#pragma unroll
            for (int i = 0; i < PRED_C; ++i) pb[i] = slabf[(128 + lane) * PRED_C + i];
            acc += cell_loss(pb, ta2, tb2);
#pragma unroll
            for (int i = 0; i < PRED_C; ++i) pb[i] = slabf[(192 + lane) * PRED_C + i];
            acc += cell_loss(pb, ta3, tb3);
        } else {
            // partial tail tile: guarded scalar path (not hit at bench shape)
            const long long cb = tile * TILE;
            for (int k = 0; k < 4; ++k) {
                long long cell = cb + 64 * k + lane;
                if (cell < ncells) {
                    float pb[PRED_C];
                    for (int i = 0; i < PRED_C; ++i) pb[i] = pred[cell * PRED_C + i];
                    const float4* gt4 = (const float4*)(tgt + cell * TGT_C);
                    acc += cell_loss(pb, gt4[0], gt4[1]);
                }
            }
            if (nextFull) issue(next);
        }
        curFull = nextFull;
        tile = next;
    }

    // wave64 shuffle reduction -> one partial per block (deterministic)
#pragma unroll
    for (int off = 32; off > 0; off >>= 1)
        acc += __shfl_down(acc, off, 64);
    if (lane == 0) wsum[wave] = acc;
    __syncthreads();
    if (t == 0) partial[blockIdx.x] = (wsum[0] + wsum[1]) + (wsum[2] + wsum[3]);
}

__global__ __launch_bounds__(256) void yolo_reduce(const float* __restrict__ partial,
                                                   float* __restrict__ out,
                                                   int nblocks, float inv_batch) {
    __shared__ float wsum[4];
    int t = threadIdx.x;
    float v = 0.0f;
    for (int i = t; i < nblocks; i += 256) v += partial[i];
#pragma unroll
    for (int off = 32; off > 0; off >>= 1)
        v += __shfl_down(v, off, 64);
    if ((t & 63) == 0) wsum[t >> 6] = v;
    __syncthreads();
    if (t == 0) out[0] = ((wsum[0] + wsum[1]) + (wsum[2] + wsum[3])) * inv_batch;
}

extern "C" void kernel_launch(void* const* d_in, const int* in_sizes, int n_in,
                              void* d_out, int out_size, void* d_ws, size_t ws_size,
                              hipStream_t stream) {
    const float* pred = (const float*)d_in[0];
    const float* tgt  = (const float*)d_in[1];
    float* out = (float*)d_out;
    float* partial = (float*)d_ws;                       // NBLOCKS floats

    long long ncells = (long long)in_sizes[1] / TGT_C;   // batch*S*S = 1,605,632
    long long batch  = ncells / 49;                      // S=7
    float inv_batch  = 1.0f / (float)batch;
    long long ntiles = (ncells + TILE - 1) / TILE;       // 6272 exact

    yolo_main<<<NBLOCKS, 256, 0, stream>>>(pred, tgt, partial, ntiles, ncells);
    yolo_reduce<<<1, 256, 0, stream>>>(partial, out, NBLOCKS, inv_batch);
}

// Round 6
// 160.210 us; speedup vs baseline: 1.2089x; 1.2089x over previous
//
#include <hip/hip_runtime.h>

// YOLO loss, fp32. predictions: (batch,7,7,13), target: (batch,7,7,8), out: scalar.
// R5 post-mortem: depth-2 pipeline was right, but 84 in-flight VGPRs vs the
// compiler's 92-VGPR occupancy target -> scratch spills (WRITE_SIZE 77 MB).
// R6: same experiment, spill-proof. Wave-tile = 64 cells (P=3.25 float4 +
// T=2 float4 in flight = ~24 VGPR), wave-private 3328B LDS slab, precise
// per-register vmcnt (no global_load_lds, no vmcnt(0) drains, no barriers),
// __launch_bounds__(256,4) caps VGPR at 128 -> no spill, 16 waves/CU.

static constexpr int PRED_C = 13;   // 5*B + C
static constexpr int TGT_C  = 8;    // 1 + 4 + 3
static constexpr float L_NOOBJ = 0.5f;
static constexpr float L_COORD = 5.0f;
static constexpr float EPSI = 1e-6f;

static constexpr int WTILE   = 64;                  // cells per wave-iteration
static constexpr int SLAB4   = WTILE * PRED_C / 4;  // 208 float4 = 3328 B/wave
static constexpr int NBLOCKS = 1024;                // 4 blocks/CU, 16 waves/CU

__device__ __forceinline__ float iou_f(float ax, float ay, float aw, float ah,
                                       float bx, float by, float bw, float bh) {
    float ax1 = ax - aw * 0.5f, ax2 = ax + aw * 0.5f;
    float ay1 = ay - ah * 0.5f, ay2 = ay + ah * 0.5f;
    float bx1 = bx - bw * 0.5f, bx2 = bx + bw * 0.5f;
    float by1 = by - bh * 0.5f, by2 = by + bh * 0.5f;
    float iw = fmaxf(fminf(ax2, bx2) - fmaxf(ax1, bx1), 0.0f);
    float ih = fmaxf(fminf(ay2, by2) - fmaxf(ay1, by1), 0.0f);
    float inter = iw * ih;
    float uni = (ax2 - ax1) * (ay2 - ay1) + (bx2 - bx1) * (by2 - by1) - inter;
    return inter / (uni + EPSI);
}

// ta = target floats 0..3 (obj,x,y,w), tb = floats 4..7 (h, c0,c1,c2)
__device__ __forceinline__ float cell_loss(const float* __restrict__ p,
                                           float4 ta, float4 tb) {
    float m  = (ta.x == 1.0f) ? 1.0f : 0.0f;
    float tx = ta.y, ty = ta.z, tw = ta.w, th = tb.x;

    float b1c = p[0],  b1x = p[1],  b1y = p[2],  b1w = p[3], b1h = p[4];
    float b2c = p[5],  b2x = p[6],  b2y = p[7],  b2w = p[8], b2h = p[9];

    float i1 = iou_f(b1x, b1y, b1w, b1h, tx, ty, tw, th);
    float i2 = iou_f(b2x, b2y, b2w, b2h, tx, ty, tw, th);
    bool pick1 = i1 > i2;
    float iou = pick1 ? i1 : i2;
    float sc  = pick1 ? b1c : b2c;
    float sx  = pick1 ? b1x : b2x;
    float sy  = pick1 ? b1y : b2y;
    float sw  = pick1 ? b1w : b2w;
    float sh  = pick1 ? b1h : b2h;
    float uc  = pick1 ? b2c : b1c;

    float dx = sx - tx, dy = sy - ty;
    // sign(w)*sqrt(|w|): copysign matches jnp.sign semantics for finite inputs.
    float dw = copysignf(sqrtf(fabsf(sw)), sw) - sqrtf(tw);
    float dh = copysignf(sqrtf(fabsf(sh)), sh) - sqrtf(th);
    float l_coord = dx * dx + dy * dy + dw * dw + dh * dh;

    float doj = sc - iou;
    float d0 = p[10] - tb.y, d1 = p[11] - tb.z, d2 = p[12] - tb.w;
    float l_cls = d0 * d0 + d1 * d1 + d2 * d2;
    float l_noobj = m * uc * uc + (1.0f - m) * (b1c * b1c + b2c * b2c);

    return m * (L_COORD * l_coord + doj * doj + l_cls) + L_NOOBJ * l_noobj;
}

__global__ __launch_bounds__(256, 4) void yolo_main(const float* __restrict__ pred,
                                                    const float* __restrict__ tgt,
                                                    float* __restrict__ partial,
                                                    long long ntiles, long long ncells) {
    __shared__ float4 sp4[4][SLAB4];   // wave-private 3328 B slab each
    __shared__ float wsum[4];

    const int t    = threadIdx.x;
    const int lane = t & 63;
    const int wave = t >> 6;
    float4* slab4 = sp4[wave];
    const float* slabf = (const float*)slab4;

    const long long nw = (long long)gridDim.x * 4;
    long long tile = (long long)blockIdx.x * 4 + wave;

    float acc = 0.0f;
    float4 P0, P1, P2, P3;   // pred tile: 208 float4 = 3x64 + 16 (lane<16)
    float4 T0, T1;           // my cell's target

    auto issue = [&](long long tl) {
        const float4* gp4 = (const float4*)pred + tl * SLAB4;
        P0 = gp4[lane];
        P1 = gp4[64 + lane];
        P2 = gp4[128 + lane];
        if (lane < 16) P3 = gp4[192 + lane];
        const float4* gt4 = (const float4*)tgt + (tl * WTILE + lane) * 2;
        T0 = gt4[0];
        T1 = gt4[1];
    };
    auto full = [&](long long tl) { return (tl + 1) * WTILE <= ncells; };

    bool curFull = false;
    if (tile < ntiles) {
        curFull = full(tile);
        if (curFull) issue(tile);      // prologue: loads in flight
    }

    while (tile < ntiles) {
        const long long next = tile + nw;
        const bool nextFull = (next < ntiles) && full(next);

        if (curFull) {
            // park pred tile in LDS (compiler waits precisely on P regs only)
            slab4[lane]       = P0;
            slab4[64 + lane]  = P1;
            slab4[128 + lane] = P2;
            if (lane < 16) slab4[192 + lane] = P3;
            float4 ta = T0, tb = T1;   // snapshot target (frees T for reissue)

            if (nextFull) issue(next); // next tile's loads fly during compute

            float pb[PRED_C];
#pragma unroll
            for (int i = 0; i < PRED_C; ++i)   // stride-13 dwords: 2-way = free
                pb[i] = slabf[lane * PRED_C + i];
            acc += cell_loss(pb, ta, tb);
        } else {
            // partial tail tile (not hit at bench shape: 64 | ncells)
            long long cell = tile * WTILE + lane;
            if (cell < ncells) {
                float pb[PRED_C];
                for (int i = 0; i < PRED_C; ++i) pb[i] = pred[cell * PRED_C + i];
                const float4* gt4 = (const float4*)(tgt + cell * TGT_C);
                acc += cell_loss(pb, gt4[0], gt4[1]);
            }
            if (nextFull) issue(next);
        }
        curFull = nextFull;
        tile = next;
    }

    // wave64 shuffle reduction -> one partial per block (deterministic)
#pragma unroll
    for (int off = 32; off > 0; off >>= 1)
        acc += __shfl_down(acc, off, 64);
    if (lane == 0) wsum[wave] = acc;
    __syncthreads();
    if (t == 0) partial[blockIdx.x] = (wsum[0] + wsum[1]) + (wsum[2] + wsum[3]);
}

__global__ __launch_bounds__(256) void yolo_reduce(const float* __restrict__ partial,
                                                   float* __restrict__ out,
                                                   int nblocks, float inv_batch) {
    __shared__ float wsum[4];
    int t = threadIdx.x;
    float v = 0.0f;
    for (int i = t; i < nblocks; i += 256) v += partial[i];
#pragma unroll
    for (int off = 32; off > 0; off >>= 1)
        v += __shfl_down(v, off, 64);
    if ((t & 63) == 0) wsum[t >> 6] = v;
    __syncthreads();
    if (t == 0) out[0] = ((wsum[0] + wsum[1]) + (wsum[2] + wsum[3])) * inv_batch;
}

extern "C" void kernel_launch(void* const* d_in, const int* in_sizes, int n_in,
                              void* d_out, int out_size, void* d_ws, size_t ws_size,
                              hipStream_t stream) {
    const float* pred = (const float*)d_in[0];
    const float* tgt  = (const float*)d_in[1];
    float* out = (float*)d_out;
    float* partial = (float*)d_ws;                       // NBLOCKS floats

    long long ncells = (long long)in_sizes[1] / TGT_C;   // batch*S*S = 1,605,632
    long long batch  = ncells / 49;                      // S=7
    float inv_batch  = 1.0f / (float)batch;
    long long ntiles = (ncells + WTILE - 1) / WTILE;     // 25,088 exact

    yolo_main<<<NBLOCKS, 256, 0, stream>>>(pred, tgt, partial, ntiles, ncells);
    yolo_reduce<<<1, 256, 0, stream>>>(partial, out, NBLOCKS, inv_batch);
}